// Round 6
// baseline (220.133 us; speedup 1.0000x reference)
//
#include <hip/hip_runtime.h>
#include <cstdint>

// B=4096, T=512, I=3, H=32, C=3
#define B_TOT 4096
#define T_LEN 512
#define CHUNK 128
#define LOG2E 1.44269504088896340736f
#define HSTR  40   // hbuf inner stride in halves (80 B): 16B-aligned b128 frags

typedef _Float16 f16x8 __attribute__((ext_vector_type(8)));
typedef _Float16 f16x4 __attribute__((ext_vector_type(4)));
typedef float    f32x4 __attribute__((ext_vector_type(4)));

__device__ __forceinline__ float ex2(float v)  { return __builtin_amdgcn_exp2f(v); }
__device__ __forceinline__ float rcp_(float v) { return __builtin_amdgcn_rcpf(v); }

// 4-batch tile, 2 waves/block, 1024 blocks -> 4 independent barrier groups/CU.
// Wave w owns hids [16w, 16w+16) via FOUR gate-MFMAs sharing one B fragment
// (B[k][n] = h[batch n&3][hid k]; cols duplicate batches x4):
//   MFMA g rows m: gate = m&3, hid = 16w + 4g + (m>>2)
// Lane (n,kq): quad (i,f,g,o) of state (batch n&3, hid 16w + 4*(n>>2) + kq),
// selected from MFMA (n>>2) -- exactly 1 state per lane, full trans utilization.
// exp2 scale folded into A rows; bias folded into x-MFMA via K-slot 3 (pad=1.0).
__global__ __launch_bounds__(128, 2)
void lstm_b4(const float* __restrict__ x,
             const float* __restrict__ W_ih,
             const float* __restrict__ W_hh,
             const float* __restrict__ b_ih,
             const float* __restrict__ b_hh,
             const float* __restrict__ W_fc,
             const float* __restrict__ b_fc,
             float* __restrict__ out)
{
    __shared__ __align__(16) _Float16 hbuf[2][4][HSTR];   // 640 B
    __shared__ __align__(16) _Float16 xbuf[CHUNK][4][4];  // 4 KB

    const int tid  = threadIdx.x;
    const int wave = tid >> 6;        // 0..1
    const int lane = tid & 63;
    const int n    = lane & 15;
    const int kq   = lane >> 4;
    const int nb   = n & 3;           // batch column
    const int tb   = blockIdx.x * 4;

    // ---- A-fragment rows (m = n) for the four gate-MFMAs ----
    const int   gate_m = n & 3;
    const int   hl_m   = n >> 2;                        // 0..3
    const float sm     = (gate_m == 2) ? (-2.0f * LOG2E) : (-LOG2E);

    f16x8 aW[4];
    f16x8 a2[4];                       // x-weights + bias (kq==0 lanes, K 0..3)
#pragma unroll
    for (int g = 0; g < 4; ++g) {
        const int R = gate_m * 32 + 16 * wave + 4 * g + hl_m;
#pragma unroll
        for (int j = 0; j < 8; ++j)
            aW[g][j] = (_Float16)(sm * W_hh[R * 32 + 8 * kq + j]);
        f16x8 t = {};
        if (kq == 0) {
            t[0] = (_Float16)(sm * W_ih[R * 3 + 0]);
            t[1] = (_Float16)(sm * W_ih[R * 3 + 1]);
            t[2] = (_Float16)(sm * W_ih[R * 3 + 2]);
            t[3] = (_Float16)(sm * (b_ih[R] + b_hh[R]));
        }
        a2[g] = t;
    }

    // my state: (batch nb, hid_s)
    const int hid_s = 16 * wave + 4 * (n >> 2) + kq;
    const int sel   = n >> 2;

    // zero h(0) buffer (hbuf[0] = 4*HSTR halves = 80 ints)
    if (tid < 80) ((int*)&hbuf[0][0][0])[tid] = 0;

    float c = 0.0f;
    const f32x4 z = {0.f, 0.f, 0.f, 0.f};
    f32x4 accx[4];   // prefetched x-contribution (incl. bias), per gate-group

    for (int tc = 0; tc < T_LEN; tc += CHUNK) {
        // ---- stage x chunk as fp16, pad slot = 1.0 (bias trick) ----
#pragma unroll
        for (int s = 0; s < 4; ++s) {
            const int idx = tid + s * 128;          // 512 (t,m) pairs
            const int tl = idx >> 2, m = idx & 3;
            const float* xp = x + ((size_t)(tb + m) * T_LEN + (tc + tl)) * 3;
            f16x4 v;
            v[0] = (_Float16)xp[0]; v[1] = (_Float16)xp[1];
            v[2] = (_Float16)xp[2]; v[3] = (_Float16)1.0f;
            *(f16x4*)&xbuf[tl][m][0] = v;
        }
        __syncthreads();

        {   // accx for first step of chunk
            const f16x4 xv = *(const f16x4*)&xbuf[0][nb][0];
            f16x8 b2 = {};
            if (kq == 0) { b2[0] = xv[0]; b2[1] = xv[1]; b2[2] = xv[2]; b2[3] = xv[3]; }
#pragma unroll
            for (int g = 0; g < 4; ++g)
                accx[g] = __builtin_amdgcn_mfma_f32_16x16x32_f16(a2[g], b2, z, 0, 0, 0);
        }

#pragma unroll 2
        for (int tt = 0; tt < CHUNK; ++tt) {
            const int p = tt & 1;   // tc is a multiple of CHUNK (even)

            // post-barrier critical path: read h -> gate MFMAs -> select -> trans -> write
            const f16x8 bh = *(const f16x8*)&hbuf[p][nb][8 * kq];
            f32x4 ac[4];
#pragma unroll
            for (int g = 0; g < 4; ++g)
                ac[g] = __builtin_amdgcn_mfma_f32_16x16x32_f16(aW[g], bh, accx[g], 0, 0, 0);

            // select my quad (sel = n>>2): 12 cndmasks
            const f32x4 lo = (sel & 2) ? ac[2] : ac[0];
            const f32x4 hi = (sel & 2) ? ac[3] : ac[1];
            const f32x4 q  = (sel & 1) ? hi : lo;

            const float iv = rcp_(1.0f + ex2(q[0]));
            const float fv = rcp_(1.0f + ex2(q[1]));
            const float gv = fmaf(2.0f, rcp_(1.0f + ex2(q[2])), -1.0f);
            const float ov = rcp_(1.0f + ex2(q[3]));

            c = fmaf(fv, c, iv * gv);
            const float th = fmaf(2.0f, rcp_(1.0f + ex2(c * (-2.0f * LOG2E))), -1.0f);
            const float h  = ov * th;

            hbuf[p ^ 1][nb][hid_s] = (_Float16)h;

            // prefetch next step's x-part (independent of h) before the barrier
            const int ttn = (tt + 1 < CHUNK) ? (tt + 1) : 0;   // boundary: dummy
            const f16x4 xv = *(const f16x4*)&xbuf[ttn][nb][0];
            f16x8 b2 = {};
            if (kq == 0) { b2[0] = xv[0]; b2[1] = xv[1]; b2[2] = xv[2]; b2[3] = xv[3]; }
#pragma unroll
            for (int g = 0; g < 4; ++g)
                accx[g] = __builtin_amdgcn_mfma_f32_16x16x32_f16(a2[g], b2, z, 0, 0, 0);

            __syncthreads();
        }
    }

    // ---- epilogue: out[tb+m][cc] = b_fc[cc] + sum_k W_fc[cc][k]*h[m][k] ----
    // final h (t=512) is in hbuf[0]; last loop barrier ordered it.
    if (tid < 12) {
        const int m = tid / 3, cc = tid % 3;
        float acc = b_fc[cc];
#pragma unroll
        for (int k = 0; k < 32; ++k)
            acc = fmaf(W_fc[cc * 32 + k], (float)hbuf[0][m][k], acc);
        out[(tb + m) * 3 + cc] = acc;
    }
}

extern "C" void kernel_launch(void* const* d_in, const int* in_sizes, int n_in,
                              void* d_out, int out_size, void* d_ws, size_t ws_size,
                              hipStream_t stream) {
    const float* x    = (const float*)d_in[0];
    const float* W_ih = (const float*)d_in[1];
    const float* W_hh = (const float*)d_in[2];
    const float* b_ih = (const float*)d_in[3];
    const float* b_hh = (const float*)d_in[4];
    const float* W_fc = (const float*)d_in[5];
    const float* b_fc = (const float*)d_in[6];
    float* out = (float*)d_out;

    dim3 grid(B_TOT / 4);    // 1024 blocks -> 4 independent barrier groups per CU
    dim3 block(128);         // 2 waves, 16 hids/wave
    lstm_b4<<<grid, block, 0, stream>>>(x, W_ih, W_hh, b_ih, b_hh, W_fc, b_fc, out);
}